// Round 12
// baseline (2398.802 us; speedup 1.0000x reference)
//
#include <hip/hip_runtime.h>
#include <cstdint>

#define T_STEPS 128
#define BATCH 64
#define IDIM 2048
#define HDIM 512
#define G4 2048   // 4*H
#define NCLS 11
#define FLAG_STRIDE 32   // ints: 128 B per WG flag line

typedef __attribute__((ext_vector_type(8))) short bf16x8;
typedef __attribute__((ext_vector_type(4))) float f32x4;
typedef __attribute__((ext_vector_type(4))) unsigned int u32x4;

__device__ __forceinline__ unsigned short f2bf(float f) {
    unsigned int u = __builtin_bit_cast(unsigned int, f);
    unsigned int r = u + 0x7FFFu + ((u >> 16) & 1u);   // RNE
    return (unsigned short)(r >> 16);
}
__device__ __forceinline__ float bf2f(unsigned short b) {
    unsigned int u = ((unsigned int)b) << 16;
    return __builtin_bit_cast(float, u);
}
__device__ __forceinline__ float sigm_fast(float x) {
    return 1.f / (1.f + __expf(-x));
}
__device__ __forceinline__ float tanh_fast(float x) {
    float e = __expf(2.f * x);        // inf-safe: x>>0 -> 1, x<<0 -> -1
    return 1.f - 2.f / (e + 1.f);
}

// async global->LDS DMA, 16B per lane (dest = wave-uniform base + lane*16)
__device__ __forceinline__ void gload_lds16(const void* g, void* lds) {
    __builtin_amdgcn_global_load_lds(
        (const __attribute__((address_space(1))) unsigned int*)g,
        (__attribute__((address_space(3))) unsigned int*)lds, 16, 0, 0);
}

// ---------------------------------------------------------------------------
// Prep (R11 unchanged)
// ---------------------------------------------------------------------------
__global__ void prep_kernel(const float* __restrict__ W_ih, const float* __restrict__ W_hh,
                            const float* __restrict__ b_ih, const float* __restrict__ b_hh,
                            const float* __restrict__ h0, const float* __restrict__ c0,
                            unsigned short* __restrict__ wih_hi, unsigned short* __restrict__ wih_lo,
                            unsigned short* __restrict__ whh_hi, unsigned short* __restrict__ whh_lo,
                            float* __restrict__ bc,
                            unsigned int* __restrict__ h_pk,
                            float* __restrict__ c_state, float* __restrict__ h_sum) {
    int idx = blockIdx.x * blockDim.x + threadIdx.x;
    int stride = gridDim.x * blockDim.x;
    for (int i = idx; i < G4 * IDIM; i += stride) {
        int np = i / IDIM, k = i - np * IDIM;
        int orig = (np & 3) * HDIM + (np >> 2);
        float f = W_ih[(size_t)orig * IDIM + k];
        unsigned short hi = f2bf(f);
        wih_hi[i] = hi;
        wih_lo[i] = f2bf(f - bf2f(hi));
    }
    for (int i = idx; i < G4 * HDIM; i += stride) {
        int np = i / HDIM, k = i - np * HDIM;
        int orig = (np & 3) * HDIM + (np >> 2);
        float f = W_hh[(size_t)orig * HDIM + k];
        unsigned short hi = f2bf(f);
        whh_hi[i] = hi;
        whh_lo[i] = f2bf(f - bf2f(hi));
    }
    for (int i = idx; i < G4; i += stride) {
        int orig = (i & 3) * HDIM + (i >> 2);
        bc[i] = b_ih[orig] + b_hh[orig];
    }
    for (int i = idx; i < BATCH * HDIM; i += stride) {
        float f = h0[i];
        unsigned short hi = f2bf(f);
        unsigned short lo = f2bf(f - bf2f(hi));
        h_pk[i] = (unsigned)hi | ((unsigned)lo << 16);   // buffer 0
        c_state[i] = c0[i];
        h_sum[i] = 0.f;
    }
}

// ---------------------------------------------------------------------------
// x split (R11 unchanged)
// ---------------------------------------------------------------------------
__global__ void prep_xsplit(const float* __restrict__ x,
                            unsigned short* __restrict__ xs_hi,
                            unsigned short* __restrict__ xs_lo) {
    int idx = blockIdx.x * blockDim.x + threadIdx.x;
    int stride = gridDim.x * blockDim.x;
    int n4 = (T_STEPS * BATCH * IDIM) / 4;
    for (int i = idx; i < n4; i += stride) {
        const float4 v = ((const float4*)x)[i];
        unsigned ux = __builtin_bit_cast(unsigned, v.x);
        unsigned uy = __builtin_bit_cast(unsigned, v.y);
        unsigned uz = __builtin_bit_cast(unsigned, v.z);
        unsigned uw = __builtin_bit_cast(unsigned, v.w);
        float rx = v.x - __builtin_bit_cast(float, ux & 0xFFFF0000u);
        float ry = v.y - __builtin_bit_cast(float, uy & 0xFFFF0000u);
        float rz = v.z - __builtin_bit_cast(float, uz & 0xFFFF0000u);
        float rw = v.w - __builtin_bit_cast(float, uw & 0xFFFF0000u);
        uint2 hw, lw;
        hw.x = __builtin_amdgcn_perm(uy, ux, 0x07060302u);
        hw.y = __builtin_amdgcn_perm(uw, uz, 0x07060302u);
        lw.x = __builtin_amdgcn_perm(__builtin_bit_cast(unsigned, ry),
                                     __builtin_bit_cast(unsigned, rx), 0x07060302u);
        lw.y = __builtin_amdgcn_perm(__builtin_bit_cast(unsigned, rw),
                                     __builtin_bit_cast(unsigned, rz), 0x07060302u);
        ((uint2*)xs_hi)[i] = hw;
        ((uint2*)xs_lo)[i] = lw;
    }
}

// ---------------------------------------------------------------------------
// xg GEMM v2 (R11 unchanged)
// ---------------------------------------------------------------------------
__global__ __launch_bounds__(256) void gemm_xg_v2(
        const unsigned short* __restrict__ xs_hi, const unsigned short* __restrict__ xs_lo,
        const unsigned short* __restrict__ wih_hi, const unsigned short* __restrict__ wih_lo,
        const float* __restrict__ bc, float* __restrict__ xg) {
    __shared__ unsigned short As_hi[128][64];
    __shared__ unsigned short As_lo[128][64];
    __shared__ unsigned short Bs_hi[128][64];
    __shared__ unsigned short Bs_lo[128][64];

    int tid = threadIdx.x;
    int w = tid >> 6, l = tid & 63;
    int lr = l & 15, lc = l >> 4;
    int bid = blockIdx.x;
    int mt = bid & 63, nt = bid >> 6;
    int m0 = mt * 128, n0 = nt * 128;
    int mq = (w >> 1) * 64, nq = (w & 1) * 64;

    int rowin = l >> 3;
    int swch  = (l & 7) ^ rowin;

    f32x4 acc[4][4] = {};

    for (int k0 = 0; k0 < IDIM; k0 += 64) {
        #pragma unroll
        for (int c = 0; c < 4; ++c) {
            int ch = w * 4 + c;
            int r  = ch * 8 + rowin;
            size_t ga = (size_t)(m0 + r) * IDIM + k0 + swch * 8;
            size_t gb = (size_t)(n0 + r) * IDIM + k0 + swch * 8;
            gload_lds16(xs_hi + ga,  (char*)As_hi + ch * 1024);
            gload_lds16(xs_lo + ga,  (char*)As_lo + ch * 1024);
            gload_lds16(wih_hi + gb, (char*)Bs_hi + ch * 1024);
            gload_lds16(wih_lo + gb, (char*)Bs_lo + ch * 1024);
        }
        __syncthreads();

        #pragma unroll
        for (int ks = 0; ks < 2; ++ks) {
            bf16x8 ah[4], al[4], bh[4], bl[4];
            int u0 = ks * 4 + lc;
            #pragma unroll
            for (int mb = 0; mb < 4; ++mb) {
                int row = mq + mb * 16 + lr;
                int off = (u0 ^ (row & 7)) * 16;
                ah[mb] = *(const bf16x8*)((const char*)&As_hi[row][0] + off);
                al[mb] = *(const bf16x8*)((const char*)&As_lo[row][0] + off);
            }
            #pragma unroll
            for (int nb = 0; nb < 4; ++nb) {
                int row = nq + nb * 16 + lr;
                int off = (u0 ^ (row & 7)) * 16;
                bh[nb] = *(const bf16x8*)((const char*)&Bs_hi[row][0] + off);
                bl[nb] = *(const bf16x8*)((const char*)&Bs_lo[row][0] + off);
            }
            #pragma unroll
            for (int mb = 0; mb < 4; ++mb)
                #pragma unroll
                for (int nb = 0; nb < 4; ++nb) {
                    acc[mb][nb] = __builtin_amdgcn_mfma_f32_16x16x32_bf16(ah[mb], bh[nb], acc[mb][nb], 0, 0, 0);
                    acc[mb][nb] = __builtin_amdgcn_mfma_f32_16x16x32_bf16(ah[mb], bl[nb], acc[mb][nb], 0, 0, 0);
                    acc[mb][nb] = __builtin_amdgcn_mfma_f32_16x16x32_bf16(al[mb], bh[nb], acc[mb][nb], 0, 0, 0);
                }
        }
        __syncthreads();
    }

    #pragma unroll
    for (int mb = 0; mb < 4; ++mb) {
        #pragma unroll
        for (int nb = 0; nb < 4; ++nb) {
            int col = n0 + nq + nb * 16 + lr;
            float bias = bc[col];
            #pragma unroll
            for (int r = 0; r < 4; ++r) {
                int row = m0 + mq + mb * 16 + lc * 4 + r;
                xg[(size_t)row * G4 + col] = acc[mb][nb][r] + bias;
            }
        }
    }
}

// ---------------------------------------------------------------------------
// xg GEMM v1 (fallback, R10)
// ---------------------------------------------------------------------------
__global__ __launch_bounds__(256) void gemm_xg(const float* __restrict__ x,
        const unsigned short* __restrict__ wih_hi, const unsigned short* __restrict__ wih_lo,
        const float* __restrict__ bc, float* __restrict__ xg) {
    __shared__ unsigned short As_hi[128][64];
    __shared__ unsigned short As_lo[128][64];
    __shared__ unsigned short Bs_hi[128][64];
    __shared__ unsigned short Bs_lo[128][64];

    int tid = threadIdx.x;
    int w = tid >> 6, l = tid & 63;
    int lr = l & 15, lc = l >> 4;
    int bid = blockIdx.x;
    int mt = bid & 63, nt = bid >> 6;
    int m0 = mt * 128, n0 = nt * 128;
    int mq = (w >> 1) * 64, nq = (w & 1) * 64;

    f32x4 acc[4][4] = {};

    for (int k0 = 0; k0 < IDIM; k0 += 64) {
        #pragma unroll
        for (int i = 0; i < 8; ++i) {
            int p = i * 256 + tid;
            int r = p >> 4, c4 = p & 15;
            const float4 v = *(const float4*)(x + (size_t)(m0 + r) * IDIM + k0 + c4 * 4);
            unsigned ux = __builtin_bit_cast(unsigned, v.x);
            unsigned uy = __builtin_bit_cast(unsigned, v.y);
            unsigned uz = __builtin_bit_cast(unsigned, v.z);
            unsigned uw = __builtin_bit_cast(unsigned, v.w);
            float rx = v.x - __builtin_bit_cast(float, ux & 0xFFFF0000u);
            float ry = v.y - __builtin_bit_cast(float, uy & 0xFFFF0000u);
            float rz = v.z - __builtin_bit_cast(float, uz & 0xFFFF0000u);
            float rw = v.w - __builtin_bit_cast(float, uw & 0xFFFF0000u);
            uint2 hw, lw;
            hw.x = __builtin_amdgcn_perm(uy, ux, 0x07060302u);
            hw.y = __builtin_amdgcn_perm(uw, uz, 0x07060302u);
            lw.x = __builtin_amdgcn_perm(__builtin_bit_cast(unsigned, ry),
                                         __builtin_bit_cast(unsigned, rx), 0x07060302u);
            lw.y = __builtin_amdgcn_perm(__builtin_bit_cast(unsigned, rw),
                                         __builtin_bit_cast(unsigned, rz), 0x07060302u);
            int off = (((c4 >> 1) ^ (r & 7)) * 16) + (c4 & 1) * 8;
            *(uint2*)((char*)&As_hi[r][0] + off) = hw;
            *(uint2*)((char*)&As_lo[r][0] + off) = lw;
        }
        #pragma unroll
        for (int i = 0; i < 4; ++i) {
            int q = i * 256 + tid;
            int n = q >> 3, c16 = q & 7;
            size_t goff = (size_t)(n0 + n) * IDIM + k0 + c16 * 8;
            int off = (c16 ^ (n & 7)) * 16;
            *(uint4*)((char*)&Bs_hi[n][0] + off) = *(const uint4*)(wih_hi + goff);
            *(uint4*)((char*)&Bs_lo[n][0] + off) = *(const uint4*)(wih_lo + goff);
        }
        __syncthreads();

        #pragma unroll
        for (int ks = 0; ks < 2; ++ks) {
            bf16x8 ah[4], al[4], bh[4], bl[4];
            int u0 = ks * 4 + lc;
            #pragma unroll
            for (int mb = 0; mb < 4; ++mb) {
                int row = mq + mb * 16 + lr;
                int off = (u0 ^ (row & 7)) * 16;
                ah[mb] = *(const bf16x8*)((const char*)&As_hi[row][0] + off);
                al[mb] = *(const bf16x8*)((const char*)&As_lo[row][0] + off);
            }
            #pragma unroll
            for (int nb = 0; nb < 4; ++nb) {
                int row = nq + nb * 16 + lr;
                int off = (u0 ^ (row & 7)) * 16;
                bh[nb] = *(const bf16x8*)((const char*)&Bs_hi[row][0] + off);
                bl[nb] = *(const bf16x8*)((const char*)&Bs_lo[row][0] + off);
            }
            #pragma unroll
            for (int mb = 0; mb < 4; ++mb)
                #pragma unroll
                for (int nb = 0; nb < 4; ++nb) {
                    acc[mb][nb] = __builtin_amdgcn_mfma_f32_16x16x32_bf16(ah[mb], bh[nb], acc[mb][nb], 0, 0, 0);
                    acc[mb][nb] = __builtin_amdgcn_mfma_f32_16x16x32_bf16(ah[mb], bl[nb], acc[mb][nb], 0, 0, 0);
                    acc[mb][nb] = __builtin_amdgcn_mfma_f32_16x16x32_bf16(al[mb], bh[nb], acc[mb][nb], 0, 0, 0);
                }
        }
        __syncthreads();
    }

    #pragma unroll
    for (int mb = 0; mb < 4; ++mb) {
        #pragma unroll
        for (int nb = 0; nb < 4; ++nb) {
            int col = n0 + nq + nb * 16 + lr;
            float bias = bc[col];
            #pragma unroll
            for (int r = 0; r < 4; ++r) {
                int row = m0 + mq + mb * 16 + lc * 4 + r;
                xg[(size_t)row * G4 + col] = acc[mb][nb][r] + bias;
            }
        }
    }
}

// ---------------------------------------------------------------------------
// lstm_step (R11 unchanged)
// ---------------------------------------------------------------------------
__global__ __launch_bounds__(256) void lstm_step(
        const unsigned short* __restrict__ whh_hi, const unsigned short* __restrict__ whh_lo,
        const float* __restrict__ xg,
        const float* __restrict__ mask_h, const float* __restrict__ mask_c,
        unsigned int* __restrict__ h_pk,
        float* __restrict__ c_state, float* __restrict__ h_sum,
        int t) {
    __shared__ float red[4][64][32];

    int g = blockIdx.x, tid = threadIdx.x;
    int w = tid >> 6, l = tid & 63;
    int lr = l & 15, lc = l >> 4;
    int cur = (t & 1) * (BATCH * HDIM);
    int nxt = ((t + 1) & 1) * (BATCH * HDIM);

    int b0_ = tid >> 3, jl0 = tid & 7, jg0 = g * 8 + jl0;
    int b1_ = (tid + 256) >> 3, jl1 = tid & 7, jg1 = g * 8 + jl1;
    float4 xgv0 = *(const float4*)(xg + (size_t)(t * BATCH + b0_) * G4 + g * 32 + jl0 * 4);
    float4 xgv1 = *(const float4*)(xg + (size_t)(t * BATCH + b1_) * G4 + g * 32 + jl1 * 4);
    size_t mi0 = (size_t)(t * BATCH + b0_) * HDIM + jg0;
    size_t mi1 = (size_t)(t * BATCH + b1_) * HDIM + jg1;
    float mh0 = mask_h[mi0], mc0 = mask_c[mi0];
    float mh1 = mask_h[mi1], mc1 = mask_c[mi1];
    float cr0 = c_state[(size_t)b0_ * HDIM + jg0];
    float cr1 = c_state[(size_t)b1_ * HDIM + jg1];

    bf16x8 bh[2][4], bl[2][4];
    #pragma unroll
    for (int nb = 0; nb < 2; ++nb)
        #pragma unroll
        for (int ks = 0; ks < 4; ++ks) {
            int n = g * 32 + nb * 16 + lr;
            int k = w * 128 + ks * 32 + lc * 8;
            bh[nb][ks] = *(const bf16x8*)(whh_hi + (size_t)n * HDIM + k);
            bl[nb][ks] = *(const bf16x8*)(whh_lo + (size_t)n * HDIM + k);
        }

    f32x4 acc[4][2] = {};
    #pragma unroll
    for (int ks = 0; ks < 4; ++ks) {
        int k = w * 128 + ks * 32 + lc * 8;
        #pragma unroll
        for (int mb = 0; mb < 4; ++mb) {
            int row = mb * 16 + lr;
            const unsigned long long* pq = (const unsigned long long*)(h_pk + cur + row * HDIM + k);
            unsigned long long q0 = pq[0], q1 = pq[1], q2 = pq[2], q3 = pq[3];
            union { unsigned int d[4]; bf16x8 v; } ahu, alu;
            {
                unsigned p0 = (unsigned)q0, p1 = (unsigned)(q0 >> 32);
                ahu.d[0] = __builtin_amdgcn_perm(p1, p0, 0x05040100u);
                alu.d[0] = __builtin_amdgcn_perm(p1, p0, 0x07060302u);
            }
            {
                unsigned p0 = (unsigned)q1, p1 = (unsigned)(q1 >> 32);
                ahu.d[1] = __builtin_amdgcn_perm(p1, p0, 0x05040100u);
                alu.d[1] = __builtin_amdgcn_perm(p1, p0, 0x07060302u);
            }
            {
                unsigned p0 = (unsigned)q2, p1 = (unsigned)(q2 >> 32);
                ahu.d[2] = __builtin_amdgcn_perm(p1, p0, 0x05040100u);
                alu.d[2] = __builtin_amdgcn_perm(p1, p0, 0x07060302u);
            }
            {
                unsigned p0 = (unsigned)q3, p1 = (unsigned)(q3 >> 32);
                ahu.d[3] = __builtin_amdgcn_perm(p1, p0, 0x05040100u);
                alu.d[3] = __builtin_amdgcn_perm(p1, p0, 0x07060302u);
            }
            bf16x8 ah = ahu.v, al = alu.v;
            #pragma unroll
            for (int nb = 0; nb < 2; ++nb) {
                acc[mb][nb] = __builtin_amdgcn_mfma_f32_16x16x32_bf16(ah, bh[nb][ks], acc[mb][nb], 0, 0, 0);
                acc[mb][nb] = __builtin_amdgcn_mfma_f32_16x16x32_bf16(ah, bl[nb][ks], acc[mb][nb], 0, 0, 0);
                acc[mb][nb] = __builtin_amdgcn_mfma_f32_16x16x32_bf16(al, bh[nb][ks], acc[mb][nb], 0, 0, 0);
            }
        }
    }
    #pragma unroll
    for (int mb = 0; mb < 4; ++mb)
        #pragma unroll
        for (int nb = 0; nb < 2; ++nb)
            #pragma unroll
            for (int r = 0; r < 4; ++r)
                red[w][mb * 16 + lc * 4 + r][nb * 16 + lr] = acc[mb][nb][r];
    __syncthreads();

    #pragma unroll
    for (int e = 0; e < 2; ++e) {
        int b  = e ? b1_ : b0_;
        int jl = e ? jl1 : jl0;
        int jg = e ? jg1 : jg0;
        int nb4 = jl * 4;
        float gi = red[0][b][nb4 + 0] + red[1][b][nb4 + 0] + red[2][b][nb4 + 0] + red[3][b][nb4 + 0];
        float gf = red[0][b][nb4 + 1] + red[1][b][nb4 + 1] + red[2][b][nb4 + 1] + red[3][b][nb4 + 1];
        float gg = red[0][b][nb4 + 2] + red[1][b][nb4 + 2] + red[2][b][nb4 + 2] + red[3][b][nb4 + 2];
        float go = red[0][b][nb4 + 3] + red[1][b][nb4 + 3] + red[2][b][nb4 + 3] + red[3][b][nb4 + 3];
        const float4 xgv = e ? xgv1 : xgv0;
        gi += xgv.x; gf += xgv.y; gg += xgv.z; go += xgv.w;
        size_t sidx = (size_t)b * HDIM + jg;
        float c_reg = e ? cr1 : cr0;
        float i_s = sigm_fast(gi);
        float f_s = sigm_fast(gf);
        float o_s = sigm_fast(go);
        float c_new = f_s * c_reg + i_s * tanh_fast(gg);
        float h_new = o_s * tanh_fast(c_new);
        h_new *= (e ? mh1 : mh0);
        c_new *= (e ? mc1 : mc0);
        c_state[sidx] = c_new;
        h_sum[sidx] += h_new;
        unsigned short hh = f2bf(h_new);
        unsigned short hl = f2bf(h_new - bf2f(hh));
        h_pk[nxt + sidx] = (unsigned)hh | ((unsigned)hl << 16);
    }
}

// ---------------------------------------------------------------------------
// Projection (R11 unchanged)
// ---------------------------------------------------------------------------
__global__ __launch_bounds__(256) void proj_kernel(
        const float* __restrict__ h_sum,
        const float* __restrict__ W_out, const float* __restrict__ b_out,
        float* __restrict__ out) {
    __shared__ float rbuf[NCLS * 256];
    int g = blockIdx.x, tid = threadIdx.x;
    float part[NCLS];
    #pragma unroll
    for (int cl = 0; cl < NCLS; ++cl) part[cl] = 0.f;
    for (int j = tid; j < HDIM; j += 256) {
        float hv = h_sum[g * HDIM + j] * (1.f / T_STEPS);
        #pragma unroll
        for (int cl = 0; cl < NCLS; ++cl)
            part[cl] += hv * W_out[cl * HDIM + j];
    }
    #pragma unroll
    for (int cl = 0; cl < NCLS; ++cl) rbuf[cl * 256 + tid] = part[cl];
    __syncthreads();
    if (tid < NCLS) {
        float s = b_out[tid];
        for (int i = 0; i < 256; ++i) s += rbuf[tid * 256 + i];
        out[g * NCLS + tid] = s;
    }
}

// ---------------------------------------------------------------------------
// SHADOW EXPERIMENT (writes scratch only; output already produced by proj).
// reinit: re-pack h(0) into h_pk buffer 0, zero shadow flags + nbad.
// ---------------------------------------------------------------------------
__global__ void reinit_kernel(const float* __restrict__ h0,
                              unsigned int* __restrict__ h_pk,
                              int* __restrict__ sh_flags, int* __restrict__ nbad) {
    int idx = blockIdx.x * blockDim.x + threadIdx.x;   // 128*256 = 32768
    if (idx < 64 * FLAG_STRIDE)
        __hip_atomic_store(sh_flags + idx, 0, __ATOMIC_RELAXED, __HIP_MEMORY_SCOPE_AGENT);
    if (idx == 0) *nbad = 0;
    float f = h0[idx];
    unsigned short hi = f2bf(f);
    unsigned short lo = f2bf(f - bf2f(hi));
    __hip_atomic_store(h_pk + idx, (unsigned)hi | ((unsigned)lo << 16),
                       __ATOMIC_RELAXED, __HIP_MEMORY_SCOPE_AGENT);
}

// ---------------------------------------------------------------------------
// shadow_rec: hardened R9 batch-split persistent recurrence.
// 64 WGs = 4 groups x 16; group gid = bid&3 owns batch rows [gid*16,+16)
// end-to-end (fan-in 16, no cross-group sync). WG m = bid>>2 computes gate
// cols [m*128,+128); wave w owns cols [m*128+w*32,+32), FULL K=512.
// Hardened: wave-0-only poll + __syncthreads (IR-level barrier: stage loads
// cannot hoist above poll); operand loads inside cell phase (no sched games).
// ---------------------------------------------------------------------------
__global__ __launch_bounds__(256, 1) void shadow_rec(
        const unsigned short* __restrict__ whh_hi, const unsigned short* __restrict__ whh_lo,
        const float* __restrict__ xg, const float* __restrict__ c0,
        const float* __restrict__ mask_h, const float* __restrict__ mask_c,
        unsigned int* __restrict__ h_pk,
        unsigned int* __restrict__ h_mean,
        int* __restrict__ flags) {
    __shared__ unsigned int hstage[16 * 512];        // 32 KB
    __shared__ float xch[4][2][16][16];              // 8 KB
    char* hsb = (char*)hstage;

    int bid = blockIdx.x, tid = threadIdx.x;
    int gid = bid & 3, m = bid >> 2;
    int w = tid >> 6, l = tid & 63;
    int lr = l & 15, lc = l >> 4;
    int row16 = l & 15, q = l >> 4;
    int brow = gid * 16 + row16;

    int jglob[2], ncol[2];
    #pragma unroll
    for (int e = 0; e < 2; ++e) {
        ncol[e] = m * 128 + w * 32 + e * 16 + q * 4;
        jglob[e] = ncol[e] >> 2;
    }
    float c_[2], ha_[2] = {0.f, 0.f};
    c_[0] = c0[(size_t)brow * HDIM + jglob[0]];
    c_[1] = c0[(size_t)brow * HDIM + jglob[1]];

    int srow = tid >> 4, scol = tid & 15;
    int sunit = scol * 4, srs = srow & 3;

    for (int t = 0; t < T_STEPS; ++t) {
        int cur = (t & 1) * (BATCH * HDIM);
        int nxt = ((t + 1) & 1) * (BATCH * HDIM);

        // (A) wave-0 polls the group's 16 producers; block barrier orders all
        if (t > 0) {
            if (tid < 16) {
                const int fb = (tid * 4 + gid) * FLAG_STRIDE;
                while (__hip_atomic_load(flags + fb, __ATOMIC_RELAXED, __HIP_MEMORY_SCOPE_AGENT) < t)
                    __builtin_amdgcn_s_sleep(1);
            }
            __syncthreads();
        }

        // (B) stage group's h(t): u64 AGENT atomic loads -> XOR-swizzled LDS
        {
            const unsigned long long* src = (const unsigned long long*)
                (h_pk + cur + (size_t)(gid * 16 + srow) * HDIM + scol * 32);
            unsigned long long qd[16];
            #pragma unroll
            for (int i = 0; i < 16; ++i)
                qd[i] = __hip_atomic_load(src + i, __ATOMIC_RELAXED, __HIP_MEMORY_SCOPE_AGENT);
            char* db = hsb + srow * 2048;
            #pragma unroll
            for (int i2 = 0; i2 < 4; ++i2) {
                u32x4 v0, v1;
                v0[0] = (unsigned)qd[i2 * 4 + 0]; v0[1] = (unsigned)(qd[i2 * 4 + 0] >> 32);
                v0[2] = (unsigned)qd[i2 * 4 + 1]; v0[3] = (unsigned)(qd[i2 * 4 + 1] >> 32);
                v1[0] = (unsigned)qd[i2 * 4 + 2]; v1[1] = (unsigned)(qd[i2 * 4 + 2] >> 32);
                v1[2] = (unsigned)qd[i2 * 4 + 3]; v1[3] = (unsigned)(qd[i2 * 4 + 3] >> 32);
                char* p = db + (((sunit + i2) ^ srs) * 32);
                *(u32x4*)p = v0;
                *(u32x4*)(p + 16) = v1;
            }
        }
        __syncthreads();

        // (C) MFMA: M=16, full K=512, 2 col-tiles per wave
        f32x4 acc0 = {}, acc1 = {};
        #pragma unroll
        for (int ks = 0; ks < 16; ++ks) {
            int uu = (ks * 4 + lc) ^ (lr & 3);
            const char* ap = hsb + lr * 2048 + uu * 32;
            u32x4 p01 = *(const u32x4*)ap;
            u32x4 p23 = *(const u32x4*)(ap + 16);
            union { unsigned int d[4]; bf16x8 v; } ahu, alu;
            ahu.d[0] = __builtin_amdgcn_perm(p01[1], p01[0], 0x05040100u);
            alu.d[0] = __builtin_amdgcn_perm(p01[1], p01[0], 0x07060302u);
            ahu.d[1] = __builtin_amdgcn_perm(p01[3], p01[2], 0x05040100u);
            alu.d[1] = __builtin_amdgcn_perm(p01[3], p01[2], 0x07060302u);
            ahu.d[2] = __builtin_amdgcn_perm(p23[1], p23[0], 0x05040100u);
            alu.d[2] = __builtin_amdgcn_perm(p23[1], p23[0], 0x07060302u);
            ahu.d[3] = __builtin_amdgcn_perm(p23[3], p23[2], 0x05040100u);
            alu.d[3] = __builtin_amdgcn_perm(p23[3], p23[2], 0x07060302u);
            bf16x8 ah = ahu.v, al = alu.v;

            size_t koff = (size_t)ks * 32 + lc * 8;
            int n0 = m * 128 + w * 32 + lr;
            bf16x8 bh0 = *(const bf16x8*)(whh_hi + (size_t)n0 * HDIM + koff);
            bf16x8 bl0 = *(const bf16x8*)(whh_lo + (size_t)n0 * HDIM + koff);
            bf16x8 bh1 = *(const bf16x8*)(whh_hi + (size_t)(n0 + 16) * HDIM + koff);
            bf16x8 bl1 = *(const bf16x8*)(whh_lo + (size_t)(n0 + 16) * HDIM + koff);

            acc0 = __builtin_amdgcn_mfma_f32_16x16x32_bf16(ah, bh0, acc0, 0, 0, 0);
            acc0 = __builtin_amdgcn_mfma_f32_16x16x32_bf16(ah, bl0, acc0, 0, 0, 0);
            acc0 = __builtin_amdgcn_mfma_f32_16x16x32_bf16(al, bh0, acc0, 0, 0, 0);
            acc1 = __builtin_amdgcn_mfma_f32_16x16x32_bf16(ah, bh1, acc1, 0, 0, 0);
            acc1 = __builtin_amdgcn_mfma_f32_16x16x32_bf16(ah, bl1, acc1, 0, 0, 0);
            acc1 = __builtin_amdgcn_mfma_f32_16x16x32_bf16(al, bh1, acc1, 0, 0, 0);
        }

        // (D) wave-local gate exchange
        #pragma unroll
        for (int r = 0; r < 4; ++r) {
            xch[w][0][lc * 4 + r][lr] = acc0[r];
            xch[w][1][lc * 4 + r][lr] = acc1[r];
        }

        // (E) cell: operands loaded here; h store via RETURNING exchange (IC)
        size_t xrow = (size_t)(t * BATCH + brow);
        #pragma unroll
        for (int e = 0; e < 2; ++e) {
            const float4 gv = *(const float4*)&xch[w][e][row16][q * 4];
            const float4 xgv = *(const float4*)(xg + xrow * G4 + ncol[e]);
            float mh = mask_h[xrow * HDIM + jglob[e]];
            float mc = mask_c[xrow * HDIM + jglob[e]];
            float gi = gv.x + xgv.x;
            float gf = gv.y + xgv.y;
            float gg = gv.z + xgv.z;
            float go = gv.w + xgv.w;
            float i_s = sigm_fast(gi);
            float f_s = sigm_fast(gf);
            float o_s = sigm_fast(go);
            float c_new = f_s * c_[e] + i_s * tanh_fast(gg);
            float h_new = o_s * tanh_fast(c_new);
            h_new *= mh;
            c_new *= mc;
            c_[e] = c_new;
            ha_[e] += h_new;
            unsigned short hh = f2bf(h_new);
            unsigned short hl = f2bf(h_new - bf2f(hh));
            unsigned int pk = (unsigned)hh | ((unsigned)hl << 16);
            unsigned int old = __hip_atomic_exchange(h_pk + nxt + (size_t)brow * HDIM + jglob[e], pk,
                                                     __ATOMIC_RELAXED, __HIP_MEMORY_SCOPE_AGENT);
            asm volatile("" :: "v"(old));   // returning form: vmcnt-ack == IC visibility
        }

        // (F) join (drains exchanges), publish
        __syncthreads();
        if (tid == 0)
            __hip_atomic_store(flags + bid * FLAG_STRIDE, t + 1, __ATOMIC_RELAXED, __HIP_MEMORY_SCOPE_AGENT);
    }

    // shadow h_mean (plain stores; kernel-end flush suffices for the checker)
    h_mean[(size_t)brow * HDIM + jglob[0]] = __builtin_bit_cast(unsigned int, ha_[0] * (1.f / T_STEPS));
    h_mean[(size_t)brow * HDIM + jglob[1]] = __builtin_bit_cast(unsigned int, ha_[1] * (1.f / T_STEPS));
}

// ---------------------------------------------------------------------------
// checker: nbad = #elements where |shadow_h_mean - h_sum/T| > 1e-3 (NaN-safe)
// ---------------------------------------------------------------------------
__global__ void check_kernel(const unsigned int* __restrict__ shm,
                             const float* __restrict__ h_sum, int* __restrict__ nbad) {
    int i = blockIdx.x * 256 + threadIdx.x;          // grid 128 -> 32768
    float a = __builtin_bit_cast(float, shm[i]);
    float b = h_sum[i] * (1.f / T_STEPS);
    float d = fabsf(a - b);
    bool bad = !(d <= 1e-3f);
    unsigned long long bal = __ballot(bad);
    if ((threadIdx.x & 63) == 0 && bal)
        atomicAdd(nbad, (int)__popcll(bal));
}

// spin: ~320+ us iff nbad>0  ->  presence in rocprof top-5 == SHADOW BROKEN
__global__ void spin_kernel(const int* __restrict__ nbad) {
    if (blockIdx.x == 0 && threadIdx.x == 0) {
        int n = *nbad;
        if (n > 0) {
            int iters = 12000 + (n >> 3);
            if (iters > 20000) iters = 20000;
            for (int i = 0; i < iters; ++i) __builtin_amdgcn_s_sleep(1);
        }
    }
}

// ---------------------------------------------------------------------------
extern "C" void kernel_launch(void* const* d_in, const int* in_sizes, int n_in,
                              void* d_out, int out_size, void* d_ws, size_t ws_size,
                              hipStream_t stream) {
    const float* x      = (const float*)d_in[0];
    const float* h0     = (const float*)d_in[1];
    const float* c0     = (const float*)d_in[2];
    const float* W_ih   = (const float*)d_in[3];
    const float* W_hh   = (const float*)d_in[4];
    const float* b_ih   = (const float*)d_in[5];
    const float* b_hh   = (const float*)d_in[6];
    const float* W_out  = (const float*)d_in[7];
    const float* b_out  = (const float*)d_in[8];
    const float* mask_h = (const float*)d_in[9];
    const float* mask_c = (const float*)d_in[10];
    float* out = (float*)d_out;

    char* ws = (char*)d_ws;
    float*          xg      = (float*)(ws + 0);                  // 67,108,864 B
    unsigned short* wih_hi  = (unsigned short*)(ws + 67108864);  // 8,388,608
    unsigned short* wih_lo  = (unsigned short*)(ws + 75497472);  // 8,388,608
    unsigned short* whh_hi  = (unsigned short*)(ws + 83886080);  // 2,097,152
    unsigned short* whh_lo  = (unsigned short*)(ws + 85983232);  // 2,097,152
    float*          bc      = (float*)(ws + 88080384);           // 8,192  (reused: shadow flags)
    unsigned int*   h_pk    = (unsigned int*)(ws + 88088576);    // 262,144 (2 bufs; reused by shadow)
    float*          c_state = (float*)(ws + 88350720);           // 131,072 (reused: shadow h_mean)
    float*          h_sum   = (float*)(ws + 88481792);           // 131,072
    unsigned short* xs_hi   = (unsigned short*)(ws + 88612864);  // 33,554,432 (reused: nbad)
    unsigned short* xs_lo   = (unsigned short*)(ws + 122167296); // 33,554,432
    const size_t NEED_V2 = 155721728;

    int*          sh_flags  = (int*)bc;           // free after gemm
    unsigned int* sh_hmean  = (unsigned int*)c_state;  // free after steps
    int*          nbad      = (int*)xs_hi;        // free after gemm

    prep_kernel<<<8192, 256, 0, stream>>>(W_ih, W_hh, b_ih, b_hh, h0, c0,
                                          wih_hi, wih_lo, whh_hi, whh_lo, bc,
                                          h_pk, c_state, h_sum);
    bool v2 = (ws_size >= NEED_V2);
    if (v2) {
        prep_xsplit<<<4096, 256, 0, stream>>>(x, xs_hi, xs_lo);
        gemm_xg_v2<<<1024, 256, 0, stream>>>(xs_hi, xs_lo, wih_hi, wih_lo, bc, xg);
    } else {
        gemm_xg<<<1024, 256, 0, stream>>>(x, wih_hi, wih_lo, bc, xg);
    }

    for (int t = 0; t < T_STEPS; ++t)
        lstm_step<<<64, 256, 0, stream>>>(whh_hi, whh_lo, xg, mask_h, mask_c,
                                          h_pk, c_state, h_sum, t);

    proj_kernel<<<64, 256, 0, stream>>>(h_sum, W_out, b_out, out);

    // ---- shadow experiment (scratch only; d_out already final) ----
    if (v2) {
        reinit_kernel<<<128, 256, 0, stream>>>(h0, h_pk, sh_flags, nbad);
        void* args[] = { &whh_hi, &whh_lo, &xg, &c0, &mask_h, &mask_c,
                         &h_pk, &sh_hmean, &sh_flags };
        hipLaunchCooperativeKernel((void*)shadow_rec, dim3(64), dim3(256), args, 0, stream);
        check_kernel<<<128, 256, 0, stream>>>(sh_hmean, h_sum, nbad);
        spin_kernel<<<1, 64, 0, stream>>>(nbad);
    }
}

// Round 14
// 1384.215 us; speedup vs baseline: 1.7330x; 1.7330x over previous
//
#include <hip/hip_runtime.h>
#include <cstdint>

#define T_STEPS 128
#define BATCH 64
#define IDIM 2048
#define HDIM 512
#define G4 2048   // 4*H
#define NCLS 11

typedef __attribute__((ext_vector_type(8))) short bf16x8;
typedef __attribute__((ext_vector_type(4))) float f32x4;

__device__ __forceinline__ unsigned short f2bf(float f) {
    unsigned int u = __builtin_bit_cast(unsigned int, f);
    unsigned int r = u + 0x7FFFu + ((u >> 16) & 1u);   // RNE
    return (unsigned short)(r >> 16);
}
__device__ __forceinline__ float bf2f(unsigned short b) {
    unsigned int u = ((unsigned int)b) << 16;
    return __builtin_bit_cast(float, u);
}
__device__ __forceinline__ float sigm_fast(float x) {
    return 1.f / (1.f + __expf(-x));
}
__device__ __forceinline__ float tanh_fast(float x) {
    float e = __expf(2.f * x);        // inf-safe: x>>0 -> 1, x<<0 -> -1
    return 1.f - 2.f / (e + 1.f);
}

// async global->LDS DMA, 16B per lane (dest = wave-uniform base + lane*16)
__device__ __forceinline__ void gload_lds16(const void* g, void* lds) {
    __builtin_amdgcn_global_load_lds(
        (const __attribute__((address_space(1))) unsigned int*)g,
        (__attribute__((address_space(3))) unsigned int*)lds, 16, 0, 0);
}

// ---------------------------------------------------------------------------
// Prep: permute gate rows to interleaved order (n' = 4*j + gate), split
// weights into bf16 hi/lo (RNE), combine biases, pack h0 into h_pk buffer 0
// (u32 = hi | lo<<16), copy c0 to c_state, zero h_sum.
// orig_row(n') = (n'&3)*512 + (n'>>2)
// ---------------------------------------------------------------------------
__global__ void prep_kernel(const float* __restrict__ W_ih, const float* __restrict__ W_hh,
                            const float* __restrict__ b_ih, const float* __restrict__ b_hh,
                            const float* __restrict__ h0, const float* __restrict__ c0,
                            unsigned short* __restrict__ wih_hi, unsigned short* __restrict__ wih_lo,
                            unsigned short* __restrict__ whh_hi, unsigned short* __restrict__ whh_lo,
                            float* __restrict__ bc,
                            unsigned int* __restrict__ h_pk,
                            float* __restrict__ c_state, float* __restrict__ h_sum) {
    int idx = blockIdx.x * blockDim.x + threadIdx.x;
    int stride = gridDim.x * blockDim.x;
    for (int i = idx; i < G4 * IDIM; i += stride) {
        int np = i / IDIM, k = i - np * IDIM;
        int orig = (np & 3) * HDIM + (np >> 2);
        float f = W_ih[(size_t)orig * IDIM + k];
        unsigned short hi = f2bf(f);
        wih_hi[i] = hi;
        wih_lo[i] = f2bf(f - bf2f(hi));
    }
    for (int i = idx; i < G4 * HDIM; i += stride) {
        int np = i / HDIM, k = i - np * HDIM;
        int orig = (np & 3) * HDIM + (np >> 2);
        float f = W_hh[(size_t)orig * HDIM + k];
        unsigned short hi = f2bf(f);
        whh_hi[i] = hi;
        whh_lo[i] = f2bf(f - bf2f(hi));
    }
    for (int i = idx; i < G4; i += stride) {
        int orig = (i & 3) * HDIM + (i >> 2);
        bc[i] = b_ih[orig] + b_hh[orig];
    }
    for (int i = idx; i < BATCH * HDIM; i += stride) {
        float f = h0[i];
        unsigned short hi = f2bf(f);
        unsigned short lo = f2bf(f - bf2f(hi));
        h_pk[i] = (unsigned)hi | ((unsigned)lo << 16);   // buffer 0
        c_state[i] = c0[i];
        h_sum[i] = 0.f;
    }
}

// ---------------------------------------------------------------------------
// x split: xs_hi = top16(x) (trunc), xs_lo = top16(x - hi) (exact residual,
// truncated). Same numerics as R10's in-gemm split (absmax 3.8e-6), done ONCE
// instead of 16x redundantly per N-block.
// ---------------------------------------------------------------------------
__global__ void prep_xsplit(const float* __restrict__ x,
                            unsigned short* __restrict__ xs_hi,
                            unsigned short* __restrict__ xs_lo) {
    int idx = blockIdx.x * blockDim.x + threadIdx.x;
    int stride = gridDim.x * blockDim.x;
    int n4 = (T_STEPS * BATCH * IDIM) / 4;
    for (int i = idx; i < n4; i += stride) {
        const float4 v = ((const float4*)x)[i];
        unsigned ux = __builtin_bit_cast(unsigned, v.x);
        unsigned uy = __builtin_bit_cast(unsigned, v.y);
        unsigned uz = __builtin_bit_cast(unsigned, v.z);
        unsigned uw = __builtin_bit_cast(unsigned, v.w);
        float rx = v.x - __builtin_bit_cast(float, ux & 0xFFFF0000u);
        float ry = v.y - __builtin_bit_cast(float, uy & 0xFFFF0000u);
        float rz = v.z - __builtin_bit_cast(float, uz & 0xFFFF0000u);
        float rw = v.w - __builtin_bit_cast(float, uw & 0xFFFF0000u);
        uint2 hw, lw;
        hw.x = __builtin_amdgcn_perm(uy, ux, 0x07060302u);
        hw.y = __builtin_amdgcn_perm(uw, uz, 0x07060302u);
        lw.x = __builtin_amdgcn_perm(__builtin_bit_cast(unsigned, ry),
                                     __builtin_bit_cast(unsigned, rx), 0x07060302u);
        lw.y = __builtin_amdgcn_perm(__builtin_bit_cast(unsigned, rw),
                                     __builtin_bit_cast(unsigned, rz), 0x07060302u);
        ((uint2*)xs_hi)[i] = hw;
        ((uint2*)xs_lo)[i] = lw;
    }
}

// ---------------------------------------------------------------------------
// xg GEMM v2: all-bf16 inputs, staging via global_load_lds (16B) with
// PRE-SWIZZLED global source (linear DMA dest + swizzled read = rule #21).
// LDS layout: [128][64] bf16, 16B unit u at row r holds global chunk u^(r&7).
// DMA chunk geometry: 1KB chunk ch covers rows ch*8..ch*8+7; lane l writes
// row ch*8+(l>>3), unit l&7 -> global chunk (l&7)^(l>>3).
// ---------------------------------------------------------------------------
__global__ __launch_bounds__(256) void gemm_xg_v2(
        const unsigned short* __restrict__ xs_hi, const unsigned short* __restrict__ xs_lo,
        const unsigned short* __restrict__ wih_hi, const unsigned short* __restrict__ wih_lo,
        const float* __restrict__ bc, float* __restrict__ xg) {
    __shared__ unsigned short As_hi[128][64];
    __shared__ unsigned short As_lo[128][64];
    __shared__ unsigned short Bs_hi[128][64];
    __shared__ unsigned short Bs_lo[128][64];

    int tid = threadIdx.x;
    int w = tid >> 6, l = tid & 63;
    int lr = l & 15, lc = l >> 4;
    int bid = blockIdx.x;
    int mt = bid & 63, nt = bid >> 6;       // 64 M-tiles x 16 N-tiles
    int m0 = mt * 128, n0 = nt * 128;
    int mq = (w >> 1) * 64, nq = (w & 1) * 64;

    int rowin = l >> 3;                     // 0..7: row within 8-row chunk
    int swch  = (l & 7) ^ rowin;            // pre-swizzled global 16B-chunk idx

    f32x4 acc[4][4] = {};

    for (int k0 = 0; k0 < IDIM; k0 += 64) {
        // stage 64KB via 16 gload_lds per wave (4 chunks x 4 arrays)
        #pragma unroll
        for (int c = 0; c < 4; ++c) {
            int ch = w * 4 + c;             // 1KB LDS chunk 0..15
            int r  = ch * 8 + rowin;        // tile row 0..127
            size_t ga = (size_t)(m0 + r) * IDIM + k0 + swch * 8;
            size_t gb = (size_t)(n0 + r) * IDIM + k0 + swch * 8;
            gload_lds16(xs_hi + ga,  (char*)As_hi + ch * 1024);
            gload_lds16(xs_lo + ga,  (char*)As_lo + ch * 1024);
            gload_lds16(wih_hi + gb, (char*)Bs_hi + ch * 1024);
            gload_lds16(wih_lo + gb, (char*)Bs_lo + ch * 1024);
        }
        __syncthreads();

        #pragma unroll
        for (int ks = 0; ks < 2; ++ks) {
            bf16x8 ah[4], al[4], bh[4], bl[4];
            int u0 = ks * 4 + lc;           // logical 16B unit 0..7
            #pragma unroll
            for (int mb = 0; mb < 4; ++mb) {
                int row = mq + mb * 16 + lr;
                int off = (u0 ^ (row & 7)) * 16;
                ah[mb] = *(const bf16x8*)((const char*)&As_hi[row][0] + off);
                al[mb] = *(const bf16x8*)((const char*)&As_lo[row][0] + off);
            }
            #pragma unroll
            for (int nb = 0; nb < 4; ++nb) {
                int row = nq + nb * 16 + lr;
                int off = (u0 ^ (row & 7)) * 16;
                bh[nb] = *(const bf16x8*)((const char*)&Bs_hi[row][0] + off);
                bl[nb] = *(const bf16x8*)((const char*)&Bs_lo[row][0] + off);
            }
            #pragma unroll
            for (int mb = 0; mb < 4; ++mb)
                #pragma unroll
                for (int nb = 0; nb < 4; ++nb) {
                    acc[mb][nb] = __builtin_amdgcn_mfma_f32_16x16x32_bf16(ah[mb], bh[nb], acc[mb][nb], 0, 0, 0);
                    acc[mb][nb] = __builtin_amdgcn_mfma_f32_16x16x32_bf16(ah[mb], bl[nb], acc[mb][nb], 0, 0, 0);
                    acc[mb][nb] = __builtin_amdgcn_mfma_f32_16x16x32_bf16(al[mb], bh[nb], acc[mb][nb], 0, 0, 0);
                }
        }
        __syncthreads();
    }

    #pragma unroll
    for (int mb = 0; mb < 4; ++mb) {
        #pragma unroll
        for (int nb = 0; nb < 4; ++nb) {
            int col = n0 + nq + nb * 16 + lr;
            float bias = bc[col];
            #pragma unroll
            for (int r = 0; r < 4; ++r) {
                int row = m0 + mq + mb * 16 + lc * 4 + r;
                xg[(size_t)row * G4 + col] = acc[mb][nb][r] + bias;
            }
        }
    }
}

// ---------------------------------------------------------------------------
// xg GEMM v1 (R10, reg-staged trunc-split) — fallback if ws is too small.
// ---------------------------------------------------------------------------
__global__ __launch_bounds__(256) void gemm_xg(const float* __restrict__ x,
        const unsigned short* __restrict__ wih_hi, const unsigned short* __restrict__ wih_lo,
        const float* __restrict__ bc, float* __restrict__ xg) {
    __shared__ unsigned short As_hi[128][64];
    __shared__ unsigned short As_lo[128][64];
    __shared__ unsigned short Bs_hi[128][64];
    __shared__ unsigned short Bs_lo[128][64];

    int tid = threadIdx.x;
    int w = tid >> 6, l = tid & 63;
    int lr = l & 15, lc = l >> 4;
    int bid = blockIdx.x;
    int mt = bid & 63, nt = bid >> 6;
    int m0 = mt * 128, n0 = nt * 128;
    int mq = (w >> 1) * 64, nq = (w & 1) * 64;

    f32x4 acc[4][4] = {};

    for (int k0 = 0; k0 < IDIM; k0 += 64) {
        #pragma unroll
        for (int i = 0; i < 8; ++i) {
            int p = i * 256 + tid;
            int r = p >> 4, c4 = p & 15;
            const float4 v = *(const float4*)(x + (size_t)(m0 + r) * IDIM + k0 + c4 * 4);
            unsigned ux = __builtin_bit_cast(unsigned, v.x);
            unsigned uy = __builtin_bit_cast(unsigned, v.y);
            unsigned uz = __builtin_bit_cast(unsigned, v.z);
            unsigned uw = __builtin_bit_cast(unsigned, v.w);
            float rx = v.x - __builtin_bit_cast(float, ux & 0xFFFF0000u);
            float ry = v.y - __builtin_bit_cast(float, uy & 0xFFFF0000u);
            float rz = v.z - __builtin_bit_cast(float, uz & 0xFFFF0000u);
            float rw = v.w - __builtin_bit_cast(float, uw & 0xFFFF0000u);
            uint2 hw, lw;
            hw.x = __builtin_amdgcn_perm(uy, ux, 0x07060302u);
            hw.y = __builtin_amdgcn_perm(uw, uz, 0x07060302u);
            lw.x = __builtin_amdgcn_perm(__builtin_bit_cast(unsigned, ry),
                                         __builtin_bit_cast(unsigned, rx), 0x07060302u);
            lw.y = __builtin_amdgcn_perm(__builtin_bit_cast(unsigned, rw),
                                         __builtin_bit_cast(unsigned, rz), 0x07060302u);
            int off = (((c4 >> 1) ^ (r & 7)) * 16) + (c4 & 1) * 8;
            *(uint2*)((char*)&As_hi[r][0] + off) = hw;
            *(uint2*)((char*)&As_lo[r][0] + off) = lw;
        }
        #pragma unroll
        for (int i = 0; i < 4; ++i) {
            int q = i * 256 + tid;
            int n = q >> 3, c16 = q & 7;
            size_t goff = (size_t)(n0 + n) * IDIM + k0 + c16 * 8;
            int off = (c16 ^ (n & 7)) * 16;
            *(uint4*)((char*)&Bs_hi[n][0] + off) = *(const uint4*)(wih_hi + goff);
            *(uint4*)((char*)&Bs_lo[n][0] + off) = *(const uint4*)(wih_lo + goff);
        }
        __syncthreads();

        #pragma unroll
        for (int ks = 0; ks < 2; ++ks) {
            bf16x8 ah[4], al[4], bh[4], bl[4];
            int u0 = ks * 4 + lc;
            #pragma unroll
            for (int mb = 0; mb < 4; ++mb) {
                int row = mq + mb * 16 + lr;
                int off = (u0 ^ (row & 7)) * 16;
                ah[mb] = *(const bf16x8*)((const char*)&As_hi[row][0] + off);
                al[mb] = *(const bf16x8*)((const char*)&As_lo[row][0] + off);
            }
            #pragma unroll
            for (int nb = 0; nb < 4; ++nb) {
                int row = nq + nb * 16 + lr;
                int off = (u0 ^ (row & 7)) * 16;
                bh[nb] = *(const bf16x8*)((const char*)&Bs_hi[row][0] + off);
                bl[nb] = *(const bf16x8*)((const char*)&Bs_lo[row][0] + off);
            }
            #pragma unroll
            for (int mb = 0; mb < 4; ++mb)
                #pragma unroll
                for (int nb = 0; nb < 4; ++nb) {
                    acc[mb][nb] = __builtin_amdgcn_mfma_f32_16x16x32_bf16(ah[mb], bh[nb], acc[mb][nb], 0, 0, 0);
                    acc[mb][nb] = __builtin_amdgcn_mfma_f32_16x16x32_bf16(ah[mb], bl[nb], acc[mb][nb], 0, 0, 0);
                    acc[mb][nb] = __builtin_amdgcn_mfma_f32_16x16x32_bf16(al[mb], bh[nb], acc[mb][nb], 0, 0, 0);
                }
        }
        __syncthreads();
    }

    #pragma unroll
    for (int mb = 0; mb < 4; ++mb) {
        #pragma unroll
        for (int nb = 0; nb < 4; ++nb) {
            int col = n0 + nq + nb * 16 + lr;
            float bias = bc[col];
            #pragma unroll
            for (int r = 0; r < 4; ++r) {
                int row = m0 + mq + mb * 16 + lc * 4 + r;
                xg[(size_t)row * G4 + col] = acc[mb][nb][r] + bias;
            }
        }
    }
}

// ---------------------------------------------------------------------------
// One LSTM time step per kernel launch (R10 + hoisted operand prefetch).
// The launch boundary is the grid barrier: stream-ordered kernels see each
// other's writes (HW-maintained coherence) — no atomics, no fences.
// ---------------------------------------------------------------------------
__global__ __launch_bounds__(256) void lstm_step(
        const unsigned short* __restrict__ whh_hi, const unsigned short* __restrict__ whh_lo,
        const float* __restrict__ xg,
        const float* __restrict__ mask_h, const float* __restrict__ mask_c,
        unsigned int* __restrict__ h_pk,
        float* __restrict__ c_state, float* __restrict__ h_sum,
        int t) {
    __shared__ float red[4][64][32];        // 32 KB: per-wave K-partials

    int g = blockIdx.x, tid = threadIdx.x;
    int w = tid >> 6, l = tid & 63;
    int lr = l & 15, lc = l >> 4;
    int cur = (t & 1) * (BATCH * HDIM);
    int nxt = ((t + 1) & 1) * (BATCH * HDIM);

    // cell-phase identities + hoisted operand prefetch (hide HBM/IC latency)
    int b0_ = tid >> 3, jl0 = tid & 7, jg0 = g * 8 + jl0;
    int b1_ = (tid + 256) >> 3, jl1 = tid & 7, jg1 = g * 8 + jl1;
    float4 xgv0 = *(const float4*)(xg + (size_t)(t * BATCH + b0_) * G4 + g * 32 + jl0 * 4);
    float4 xgv1 = *(const float4*)(xg + (size_t)(t * BATCH + b1_) * G4 + g * 32 + jl1 * 4);
    size_t mi0 = (size_t)(t * BATCH + b0_) * HDIM + jg0;
    size_t mi1 = (size_t)(t * BATCH + b1_) * HDIM + jg1;
    float mh0 = mask_h[mi0], mc0 = mask_c[mi0];
    float mh1 = mask_h[mi1], mc1 = mask_c[mi1];
    float cr0 = c_state[(size_t)b0_ * HDIM + jg0];
    float cr1 = c_state[(size_t)b1_ * HDIM + jg1];

    // B fragments (Whh'' slice) — L2-resident across steps (same 64 KB/WG)
    bf16x8 bh[2][4], bl[2][4];
    #pragma unroll
    for (int nb = 0; nb < 2; ++nb)
        #pragma unroll
        for (int ks = 0; ks < 4; ++ks) {
            int n = g * 32 + nb * 16 + lr;
            int k = w * 128 + ks * 32 + lc * 8;
            bh[nb][ks] = *(const bf16x8*)(whh_hi + (size_t)n * HDIM + k);
            bl[nb][ks] = *(const bf16x8*)(whh_lo + (size_t)n * HDIM + k);
        }

    f32x4 acc[4][2] = {};
    #pragma unroll
    for (int ks = 0; ks < 4; ++ks) {
        int k = w * 128 + ks * 32 + lc * 8;
        #pragma unroll
        for (int mb = 0; mb < 4; ++mb) {
            int row = mb * 16 + lr;
            const unsigned long long* pq = (const unsigned long long*)(h_pk + cur + row * HDIM + k);
            unsigned long long q0 = pq[0], q1 = pq[1], q2 = pq[2], q3 = pq[3];
            union { unsigned int d[4]; bf16x8 v; } ahu, alu;
            {
                unsigned p0 = (unsigned)q0, p1 = (unsigned)(q0 >> 32);
                ahu.d[0] = __builtin_amdgcn_perm(p1, p0, 0x05040100u);
                alu.d[0] = __builtin_amdgcn_perm(p1, p0, 0x07060302u);
            }
            {
                unsigned p0 = (unsigned)q1, p1 = (unsigned)(q1 >> 32);
                ahu.d[1] = __builtin_amdgcn_perm(p1, p0, 0x05040100u);
                alu.d[1] = __builtin_amdgcn_perm(p1, p0, 0x07060302u);
            }
            {
                unsigned p0 = (unsigned)q2, p1 = (unsigned)(q2 >> 32);
                ahu.d[2] = __builtin_amdgcn_perm(p1, p0, 0x05040100u);
                alu.d[2] = __builtin_amdgcn_perm(p1, p0, 0x07060302u);
            }
            {
                unsigned p0 = (unsigned)q3, p1 = (unsigned)(q3 >> 32);
                ahu.d[3] = __builtin_amdgcn_perm(p1, p0, 0x05040100u);
                alu.d[3] = __builtin_amdgcn_perm(p1, p0, 0x07060302u);
            }
            bf16x8 ah = ahu.v, al = alu.v;
            #pragma unroll
            for (int nb = 0; nb < 2; ++nb) {
                acc[mb][nb] = __builtin_amdgcn_mfma_f32_16x16x32_bf16(ah, bh[nb][ks], acc[mb][nb], 0, 0, 0);
                acc[mb][nb] = __builtin_amdgcn_mfma_f32_16x16x32_bf16(ah, bl[nb][ks], acc[mb][nb], 0, 0, 0);
                acc[mb][nb] = __builtin_amdgcn_mfma_f32_16x16x32_bf16(al, bh[nb][ks], acc[mb][nb], 0, 0, 0);
            }
        }
    }
    #pragma unroll
    for (int mb = 0; mb < 4; ++mb)
        #pragma unroll
        for (int nb = 0; nb < 2; ++nb)
            #pragma unroll
            for (int r = 0; r < 4; ++r)
                red[w][mb * 16 + lc * 4 + r][nb * 16 + lr] = acc[mb][nb][r];
    __syncthreads();

    // cell phase: 2 cells per thread
    #pragma unroll
    for (int e = 0; e < 2; ++e) {
        int b  = e ? b1_ : b0_;
        int jl = e ? jl1 : jl0;
        int jg = e ? jg1 : jg0;
        int nb4 = jl * 4;
        float gi = red[0][b][nb4 + 0] + red[1][b][nb4 + 0] + red[2][b][nb4 + 0] + red[3][b][nb4 + 0];
        float gf = red[0][b][nb4 + 1] + red[1][b][nb4 + 1] + red[2][b][nb4 + 1] + red[3][b][nb4 + 1];
        float gg = red[0][b][nb4 + 2] + red[1][b][nb4 + 2] + red[2][b][nb4 + 2] + red[3][b][nb4 + 2];
        float go = red[0][b][nb4 + 3] + red[1][b][nb4 + 3] + red[2][b][nb4 + 3] + red[3][b][nb4 + 3];
        const float4 xgv = e ? xgv1 : xgv0;
        gi += xgv.x; gf += xgv.y; gg += xgv.z; go += xgv.w;
        size_t sidx = (size_t)b * HDIM + jg;
        float c_reg = e ? cr1 : cr0;
        float i_s = sigm_fast(gi);
        float f_s = sigm_fast(gf);
        float o_s = sigm_fast(go);
        float c_new = f_s * c_reg + i_s * tanh_fast(gg);
        float h_new = o_s * tanh_fast(c_new);
        h_new *= (e ? mh1 : mh0);
        c_new *= (e ? mc1 : mc0);
        c_state[sidx] = c_new;
        h_sum[sidx] += h_new;
        unsigned short hh = f2bf(h_new);
        unsigned short hl = f2bf(h_new - bf2f(hh));
        h_pk[nxt + sidx] = (unsigned)hh | ((unsigned)hl << 16);
    }
}

// ---------------------------------------------------------------------------
// Projection: WG g handles batch b = g -> out[g*11 + cl]
// ---------------------------------------------------------------------------
__global__ __launch_bounds__(256) void proj_kernel(
        const float* __restrict__ h_sum,
        const float* __restrict__ W_out, const float* __restrict__ b_out,
        float* __restrict__ out) {
    __shared__ float rbuf[NCLS * 256];
    int g = blockIdx.x, tid = threadIdx.x;
    float part[NCLS];
    #pragma unroll
    for (int cl = 0; cl < NCLS; ++cl) part[cl] = 0.f;
    for (int j = tid; j < HDIM; j += 256) {
        float hv = h_sum[g * HDIM + j] * (1.f / T_STEPS);
        #pragma unroll
        for (int cl = 0; cl < NCLS; ++cl)
            part[cl] += hv * W_out[cl * HDIM + j];
    }
    #pragma unroll
    for (int cl = 0; cl < NCLS; ++cl) rbuf[cl * 256 + tid] = part[cl];
    __syncthreads();
    if (tid < NCLS) {
        float s = b_out[tid];
        for (int i = 0; i < 256; ++i) s += rbuf[tid * 256 + i];
        out[g * NCLS + tid] = s;
    }
}

// ---------------------------------------------------------------------------
extern "C" void kernel_launch(void* const* d_in, const int* in_sizes, int n_in,
                              void* d_out, int out_size, void* d_ws, size_t ws_size,
                              hipStream_t stream) {
    const float* x      = (const float*)d_in[0];
    const float* h0     = (const float*)d_in[1];
    const float* c0     = (const float*)d_in[2];
    const float* W_ih   = (const float*)d_in[3];
    const float* W_hh   = (const float*)d_in[4];
    const float* b_ih   = (const float*)d_in[5];
    const float* b_hh   = (const float*)d_in[6];
    const float* W_out  = (const float*)d_in[7];
    const float* b_out  = (const float*)d_in[8];
    const float* mask_h = (const float*)d_in[9];
    const float* mask_c = (const float*)d_in[10];
    float* out = (float*)d_out;

    char* ws = (char*)d_ws;
    float*          xg      = (float*)(ws + 0);                  // 67,108,864 B
    unsigned short* wih_hi  = (unsigned short*)(ws + 67108864);  // 8,388,608
    unsigned short* wih_lo  = (unsigned short*)(ws + 75497472);  // 8,388,608
    unsigned short* whh_hi  = (unsigned short*)(ws + 83886080);  // 2,097,152
    unsigned short* whh_lo  = (unsigned short*)(ws + 85983232);  // 2,097,152
    float*          bc      = (float*)(ws + 88080384);           // 8,192
    unsigned int*   h_pk    = (unsigned int*)(ws + 88088576);    // 262,144 (2 bufs)
    float*          c_state = (float*)(ws + 88350720);           // 131,072
    float*          h_sum   = (float*)(ws + 88481792);           // 131,072
    unsigned short* xs_hi   = (unsigned short*)(ws + 88612864);  // 33,554,432
    unsigned short* xs_lo   = (unsigned short*)(ws + 122167296); // 33,554,432
    const size_t NEED_V2 = 155721728;

    prep_kernel<<<8192, 256, 0, stream>>>(W_ih, W_hh, b_ih, b_hh, h0, c0,
                                          wih_hi, wih_lo, whh_hi, whh_lo, bc,
                                          h_pk, c_state, h_sum);
    if (ws_size >= NEED_V2) {
        prep_xsplit<<<4096, 256, 0, stream>>>(x, xs_hi, xs_lo);
        gemm_xg_v2<<<1024, 256, 0, stream>>>(xs_hi, xs_lo, wih_hi, wih_lo, bc, xg);
    } else {
        gemm_xg<<<1024, 256, 0, stream>>>(x, wih_hi, wih_lo, bc, xg);
    }

    for (int t = 0; t < T_STEPS; ++t)
        lstm_step<<<64, 256, 0, stream>>>(whh_hi, whh_lo, xg, mask_h, mask_c,
                                          h_pk, c_state, h_sum, t);

    proj_kernel<<<64, 256, 0, stream>>>(h_sum, W_out, b_out, out);
}

// Round 15
// 1143.461 us; speedup vs baseline: 2.0978x; 1.2105x over previous
//
#include <hip/hip_runtime.h>
#include <cstdint>

#define T_STEPS 128
#define BATCH 64
#define IDIM 2048
#define HDIM 512
#define G4 2048   // 4*H
#define NCLS 11

typedef __attribute__((ext_vector_type(8))) short bf16x8;
typedef __attribute__((ext_vector_type(4))) float f32x4;

__device__ __forceinline__ unsigned short f2bf(float f) {
    unsigned int u = __builtin_bit_cast(unsigned int, f);
    unsigned int r = u + 0x7FFFu + ((u >> 16) & 1u);   // RNE
    return (unsigned short)(r >> 16);
}
__device__ __forceinline__ float bf2f(unsigned short b) {
    unsigned int u = ((unsigned int)b) << 16;
    return __builtin_bit_cast(float, u);
}
__device__ __forceinline__ float sigm_fast(float x) {
    return 1.f / (1.f + __expf(-x));
}
__device__ __forceinline__ float tanh_fast(float x) {
    float e = __expf(2.f * x);        // inf-safe: x>>0 -> 1, x<<0 -> -1
    return 1.f - 2.f / (e + 1.f);
}

// async global->LDS DMA, 16B per lane (dest = wave-uniform base + lane*16)
__device__ __forceinline__ void gload_lds16(const void* g, void* lds) {
    __builtin_amdgcn_global_load_lds(
        (const __attribute__((address_space(1))) unsigned int*)g,
        (__attribute__((address_space(3))) unsigned int*)lds, 16, 0, 0);
}

// ---------------------------------------------------------------------------
// Prep: permute gate rows to interleaved order (n' = 4*j + gate), split
// weights into bf16 hi/lo (RNE), combine biases, pack h0 into h_pk buffer 0
// (u32 = hi | lo<<16), copy c0 to c_state, zero h_sum.
// orig_row(n') = (n'&3)*512 + (n'>>2)
// ---------------------------------------------------------------------------
__global__ void prep_kernel(const float* __restrict__ W_ih, const float* __restrict__ W_hh,
                            const float* __restrict__ b_ih, const float* __restrict__ b_hh,
                            const float* __restrict__ h0, const float* __restrict__ c0,
                            unsigned short* __restrict__ wih_hi, unsigned short* __restrict__ wih_lo,
                            unsigned short* __restrict__ whh_hi, unsigned short* __restrict__ whh_lo,
                            float* __restrict__ bc,
                            unsigned int* __restrict__ h_pk,
                            float* __restrict__ c_state, float* __restrict__ h_sum) {
    int idx = blockIdx.x * blockDim.x + threadIdx.x;
    int stride = gridDim.x * blockDim.x;
    for (int i = idx; i < G4 * IDIM; i += stride) {
        int np = i / IDIM, k = i - np * IDIM;
        int orig = (np & 3) * HDIM + (np >> 2);
        float f = W_ih[(size_t)orig * IDIM + k];
        unsigned short hi = f2bf(f);
        wih_hi[i] = hi;
        wih_lo[i] = f2bf(f - bf2f(hi));
    }
    for (int i = idx; i < G4 * HDIM; i += stride) {
        int np = i / HDIM, k = i - np * HDIM;
        int orig = (np & 3) * HDIM + (np >> 2);
        float f = W_hh[(size_t)orig * HDIM + k];
        unsigned short hi = f2bf(f);
        whh_hi[i] = hi;
        whh_lo[i] = f2bf(f - bf2f(hi));
    }
    for (int i = idx; i < G4; i += stride) {
        int orig = (i & 3) * HDIM + (i >> 2);
        bc[i] = b_ih[orig] + b_hh[orig];
    }
    for (int i = idx; i < BATCH * HDIM; i += stride) {
        float f = h0[i];
        unsigned short hi = f2bf(f);
        unsigned short lo = f2bf(f - bf2f(hi));
        h_pk[i] = (unsigned)hi | ((unsigned)lo << 16);   // buffer 0
        c_state[i] = c0[i];
        h_sum[i] = 0.f;
    }
}

// ---------------------------------------------------------------------------
// x split: xs_hi = top16(x) (trunc), xs_lo = top16(x - hi) (exact residual,
// truncated). Same numerics as R10's in-gemm split (absmax 3.8e-6).
// ---------------------------------------------------------------------------
__global__ void prep_xsplit(const float* __restrict__ x,
                            unsigned short* __restrict__ xs_hi,
                            unsigned short* __restrict__ xs_lo) {
    int idx = blockIdx.x * blockDim.x + threadIdx.x;
    int stride = gridDim.x * blockDim.x;
    int n4 = (T_STEPS * BATCH * IDIM) / 4;
    for (int i = idx; i < n4; i += stride) {
        const float4 v = ((const float4*)x)[i];
        unsigned ux = __builtin_bit_cast(unsigned, v.x);
        unsigned uy = __builtin_bit_cast(unsigned, v.y);
        unsigned uz = __builtin_bit_cast(unsigned, v.z);
        unsigned uw = __builtin_bit_cast(unsigned, v.w);
        float rx = v.x - __builtin_bit_cast(float, ux & 0xFFFF0000u);
        float ry = v.y - __builtin_bit_cast(float, uy & 0xFFFF0000u);
        float rz = v.z - __builtin_bit_cast(float, uz & 0xFFFF0000u);
        float rw = v.w - __builtin_bit_cast(float, uw & 0xFFFF0000u);
        uint2 hw, lw;
        hw.x = __builtin_amdgcn_perm(uy, ux, 0x07060302u);
        hw.y = __builtin_amdgcn_perm(uw, uz, 0x07060302u);
        lw.x = __builtin_amdgcn_perm(__builtin_bit_cast(unsigned, ry),
                                     __builtin_bit_cast(unsigned, rx), 0x07060302u);
        lw.y = __builtin_amdgcn_perm(__builtin_bit_cast(unsigned, rw),
                                     __builtin_bit_cast(unsigned, rz), 0x07060302u);
        ((uint2*)xs_hi)[i] = hw;
        ((uint2*)xs_lo)[i] = lw;
    }
}

// ---------------------------------------------------------------------------
// xg GEMM v2 (R11, unchanged): global_load_lds + pre-swizzled source
// ---------------------------------------------------------------------------
__global__ __launch_bounds__(256) void gemm_xg_v2(
        const unsigned short* __restrict__ xs_hi, const unsigned short* __restrict__ xs_lo,
        const unsigned short* __restrict__ wih_hi, const unsigned short* __restrict__ wih_lo,
        const float* __restrict__ bc, float* __restrict__ xg) {
    __shared__ unsigned short As_hi[128][64];
    __shared__ unsigned short As_lo[128][64];
    __shared__ unsigned short Bs_hi[128][64];
    __shared__ unsigned short Bs_lo[128][64];

    int tid = threadIdx.x;
    int w = tid >> 6, l = tid & 63;
    int lr = l & 15, lc = l >> 4;
    int bid = blockIdx.x;
    int mt = bid & 63, nt = bid >> 6;       // 64 M-tiles x 16 N-tiles
    int m0 = mt * 128, n0 = nt * 128;
    int mq = (w >> 1) * 64, nq = (w & 1) * 64;

    int rowin = l >> 3;                     // 0..7: row within 8-row chunk
    int swch  = (l & 7) ^ rowin;            // pre-swizzled global 16B-chunk idx

    f32x4 acc[4][4] = {};

    for (int k0 = 0; k0 < IDIM; k0 += 64) {
        #pragma unroll
        for (int c = 0; c < 4; ++c) {
            int ch = w * 4 + c;             // 1KB LDS chunk 0..15
            int r  = ch * 8 + rowin;        // tile row 0..127
            size_t ga = (size_t)(m0 + r) * IDIM + k0 + swch * 8;
            size_t gb = (size_t)(n0 + r) * IDIM + k0 + swch * 8;
            gload_lds16(xs_hi + ga,  (char*)As_hi + ch * 1024);
            gload_lds16(xs_lo + ga,  (char*)As_lo + ch * 1024);
            gload_lds16(wih_hi + gb, (char*)Bs_hi + ch * 1024);
            gload_lds16(wih_lo + gb, (char*)Bs_lo + ch * 1024);
        }
        __syncthreads();

        #pragma unroll
        for (int ks = 0; ks < 2; ++ks) {
            bf16x8 ah[4], al[4], bh[4], bl[4];
            int u0 = ks * 4 + lc;           // logical 16B unit 0..7
            #pragma unroll
            for (int mb = 0; mb < 4; ++mb) {
                int row = mq + mb * 16 + lr;
                int off = (u0 ^ (row & 7)) * 16;
                ah[mb] = *(const bf16x8*)((const char*)&As_hi[row][0] + off);
                al[mb] = *(const bf16x8*)((const char*)&As_lo[row][0] + off);
            }
            #pragma unroll
            for (int nb = 0; nb < 4; ++nb) {
                int row = nq + nb * 16 + lr;
                int off = (u0 ^ (row & 7)) * 16;
                bh[nb] = *(const bf16x8*)((const char*)&Bs_hi[row][0] + off);
                bl[nb] = *(const bf16x8*)((const char*)&Bs_lo[row][0] + off);
            }
            #pragma unroll
            for (int mb = 0; mb < 4; ++mb)
                #pragma unroll
                for (int nb = 0; nb < 4; ++nb) {
                    acc[mb][nb] = __builtin_amdgcn_mfma_f32_16x16x32_bf16(ah[mb], bh[nb], acc[mb][nb], 0, 0, 0);
                    acc[mb][nb] = __builtin_amdgcn_mfma_f32_16x16x32_bf16(ah[mb], bl[nb], acc[mb][nb], 0, 0, 0);
                    acc[mb][nb] = __builtin_amdgcn_mfma_f32_16x16x32_bf16(al[mb], bh[nb], acc[mb][nb], 0, 0, 0);
                }
        }
        __syncthreads();
    }

    #pragma unroll
    for (int mb = 0; mb < 4; ++mb) {
        #pragma unroll
        for (int nb = 0; nb < 4; ++nb) {
            int col = n0 + nq + nb * 16 + lr;
            float bias = bc[col];
            #pragma unroll
            for (int r = 0; r < 4; ++r) {
                int row = m0 + mq + mb * 16 + lc * 4 + r;
                xg[(size_t)row * G4 + col] = acc[mb][nb][r] + bias;
            }
        }
    }
}

// ---------------------------------------------------------------------------
// xg GEMM v1 (R10, reg-staged trunc-split) — fallback if ws is too small.
// ---------------------------------------------------------------------------
__global__ __launch_bounds__(256) void gemm_xg(const float* __restrict__ x,
        const unsigned short* __restrict__ wih_hi, const unsigned short* __restrict__ wih_lo,
        const float* __restrict__ bc, float* __restrict__ xg) {
    __shared__ unsigned short As_hi[128][64];
    __shared__ unsigned short As_lo[128][64];
    __shared__ unsigned short Bs_hi[128][64];
    __shared__ unsigned short Bs_lo[128][64];

    int tid = threadIdx.x;
    int w = tid >> 6, l = tid & 63;
    int lr = l & 15, lc = l >> 4;
    int bid = blockIdx.x;
    int mt = bid & 63, nt = bid >> 6;
    int m0 = mt * 128, n0 = nt * 128;
    int mq = (w >> 1) * 64, nq = (w & 1) * 64;

    f32x4 acc[4][4] = {};

    for (int k0 = 0; k0 < IDIM; k0 += 64) {
        #pragma unroll
        for (int i = 0; i < 8; ++i) {
            int p = i * 256 + tid;
            int r = p >> 4, c4 = p & 15;
            const float4 v = *(const float4*)(x + (size_t)(m0 + r) * IDIM + k0 + c4 * 4);
            unsigned ux = __builtin_bit_cast(unsigned, v.x);
            unsigned uy = __builtin_bit_cast(unsigned, v.y);
            unsigned uz = __builtin_bit_cast(unsigned, v.z);
            unsigned uw = __builtin_bit_cast(unsigned, v.w);
            float rx = v.x - __builtin_bit_cast(float, ux & 0xFFFF0000u);
            float ry = v.y - __builtin_bit_cast(float, uy & 0xFFFF0000u);
            float rz = v.z - __builtin_bit_cast(float, uz & 0xFFFF0000u);
            float rw = v.w - __builtin_bit_cast(float, uw & 0xFFFF0000u);
            uint2 hw, lw;
            hw.x = __builtin_amdgcn_perm(uy, ux, 0x07060302u);
            hw.y = __builtin_amdgcn_perm(uw, uz, 0x07060302u);
            lw.x = __builtin_amdgcn_perm(__builtin_bit_cast(unsigned, ry),
                                         __builtin_bit_cast(unsigned, rx), 0x07060302u);
            lw.y = __builtin_amdgcn_perm(__builtin_bit_cast(unsigned, rw),
                                         __builtin_bit_cast(unsigned, rz), 0x07060302u);
            int off = (((c4 >> 1) ^ (r & 7)) * 16) + (c4 & 1) * 8;
            *(uint2*)((char*)&As_hi[r][0] + off) = hw;
            *(uint2*)((char*)&As_lo[r][0] + off) = lw;
        }
        #pragma unroll
        for (int i = 0; i < 4; ++i) {
            int q = i * 256 + tid;
            int n = q >> 3, c16 = q & 7;
            size_t goff = (size_t)(n0 + n) * IDIM + k0 + c16 * 8;
            int off = (c16 ^ (n & 7)) * 16;
            *(uint4*)((char*)&Bs_hi[n][0] + off) = *(const uint4*)(wih_hi + goff);
            *(uint4*)((char*)&Bs_lo[n][0] + off) = *(const uint4*)(wih_lo + goff);
        }
        __syncthreads();

        #pragma unroll
        for (int ks = 0; ks < 2; ++ks) {
            bf16x8 ah[4], al[4], bh[4], bl[4];
            int u0 = ks * 4 + lc;
            #pragma unroll
            for (int mb = 0; mb < 4; ++mb) {
                int row = mq + mb * 16 + lr;
                int off = (u0 ^ (row & 7)) * 16;
                ah[mb] = *(const bf16x8*)((const char*)&As_hi[row][0] + off);
                al[mb] = *(const bf16x8*)((const char*)&As_lo[row][0] + off);
            }
            #pragma unroll
            for (int nb = 0; nb < 4; ++nb) {
                int row = nq + nb * 16 + lr;
                int off = (u0 ^ (row & 7)) * 16;
                bh[nb] = *(const bf16x8*)((const char*)&Bs_hi[row][0] + off);
                bl[nb] = *(const bf16x8*)((const char*)&Bs_lo[row][0] + off);
            }
            #pragma unroll
            for (int mb = 0; mb < 4; ++mb)
                #pragma unroll
                for (int nb = 0; nb < 4; ++nb) {
                    acc[mb][nb] = __builtin_amdgcn_mfma_f32_16x16x32_bf16(ah[mb], bh[nb], acc[mb][nb], 0, 0, 0);
                    acc[mb][nb] = __builtin_amdgcn_mfma_f32_16x16x32_bf16(ah[mb], bl[nb], acc[mb][nb], 0, 0, 0);
                    acc[mb][nb] = __builtin_amdgcn_mfma_f32_16x16x32_bf16(al[mb], bh[nb], acc[mb][nb], 0, 0, 0);
                }
        }
        __syncthreads();
    }

    #pragma unroll
    for (int mb = 0; mb < 4; ++mb) {
        #pragma unroll
        for (int nb = 0; nb < 4; ++nb) {
            int col = n0 + nq + nb * 16 + lr;
            float bias = bc[col];
            #pragma unroll
            for (int r = 0; r < 4; ++r) {
                int row = m0 + mq + mb * 16 + lc * 4 + r;
                xg[(size_t)row * G4 + col] = acc[mb][nb][r] + bias;
            }
        }
    }
}

// ---------------------------------------------------------------------------
// One LSTM time step per kernel launch. v3: h-gather via global_load_lds DMA
// (32 x 1KB per wave, all in flight -> one latency) with swizzle-pre-applied
// per-lane global source (rule #21, gemm_xg_v2-proven technique).
// LDS quarter layout: row r (0..63), physical 16B unit p at byte r*512+p*16
// holds logical unit u = (p&24) | ((p&7) ^ (r&7))  (self-inverse).
// Fragment reads at p = ks*8 + ((2lc [+1]) ^ (lr&7)): 16-lane phase = 8
// quadrants x 2 rows = 2-way = free. red[] aliases first 8KB of each wave's
// quarter (same-wave reads precede writes; DS ops wave-ordered).
// ---------------------------------------------------------------------------
__global__ __launch_bounds__(256) void lstm_step(
        const unsigned short* __restrict__ whh_hi, const unsigned short* __restrict__ whh_lo,
        const float* __restrict__ xg,
        const float* __restrict__ mask_h, const float* __restrict__ mask_c,
        unsigned int* __restrict__ h_pk,
        float* __restrict__ c_state, float* __restrict__ h_sum,
        int t) {
    __shared__ unsigned int hs[4][8192];    // 128 KB: 4 wave-quarters of h(t)

    int g = blockIdx.x, tid = threadIdx.x;
    int w = tid >> 6, l = tid & 63;
    int lr = l & 15, lc = l >> 4;
    int cur = (t & 1) * (BATCH * HDIM);
    int nxt = ((t + 1) & 1) * (BATCH * HDIM);

    // (1) DMA-stage this wave's K-quarter [w*128,+128) u32 of all 64 rows.
    //     Instr i stages rows {2i, 2i+1} (1KB linear LDS); lane -> (row, p).
    {
        int hl = l >> 5;                    // row within the pair
        int p  = l & 31;                    // physical 16B unit
        #pragma unroll
        for (int i = 0; i < 32; ++i) {
            int row = i * 2 + hl;
            int u = (p & 24) | ((p & 7) ^ (row & 7));    // logical unit (pre-swizzled src)
            const unsigned int* src = h_pk + cur + row * HDIM + w * 128 + u * 4;
            gload_lds16(src, (char*)&hs[w][0] + i * 1024);
        }
    }

    // (2) operand prefetch + W fragments (overlap DMA latency)
    int b0_ = tid >> 3, jl0 = tid & 7, jg0 = g * 8 + jl0;
    int b1_ = (tid + 256) >> 3, jl1 = tid & 7, jg1 = g * 8 + jl1;
    float4 xgv0 = *(const float4*)(xg + (size_t)(t * BATCH + b0_) * G4 + g * 32 + jl0 * 4);
    float4 xgv1 = *(const float4*)(xg + (size_t)(t * BATCH + b1_) * G4 + g * 32 + jl1 * 4);
    size_t mi0 = (size_t)(t * BATCH + b0_) * HDIM + jg0;
    size_t mi1 = (size_t)(t * BATCH + b1_) * HDIM + jg1;
    float mh0 = mask_h[mi0], mc0 = mask_c[mi0];
    float mh1 = mask_h[mi1], mc1 = mask_c[mi1];
    float cr0 = c_state[(size_t)b0_ * HDIM + jg0];
    float cr1 = c_state[(size_t)b1_ * HDIM + jg1];

    bf16x8 bh[2][4], bl[2][4];
    #pragma unroll
    for (int nb = 0; nb < 2; ++nb)
        #pragma unroll
        for (int ks = 0; ks < 4; ++ks) {
            int n = g * 32 + nb * 16 + lr;
            int k = w * 128 + ks * 32 + lc * 8;
            bh[nb][ks] = *(const bf16x8*)(whh_hi + (size_t)n * HDIM + k);
            bl[nb][ks] = *(const bf16x8*)(whh_lo + (size_t)n * HDIM + k);
        }

    __syncthreads();                        // drains DMA (vmcnt0) + joins WG

    // (3) MFMA from swizzled LDS (2-way banks = free)
    f32x4 acc[4][2] = {};
    #pragma unroll
    for (int ks = 0; ks < 4; ++ks) {
        #pragma unroll
        for (int mb = 0; mb < 4; ++mb) {
            int row = mb * 16 + lr;
            const char* base = (const char*)&hs[w][0] + row * 512;
            int x = lr & 7;
            uint4 A = *(const uint4*)(base + (ks * 8 + ((2 * lc    ) ^ x)) * 16);
            uint4 B = *(const uint4*)(base + (ks * 8 + ((2 * lc + 1) ^ x)) * 16);
            union { unsigned int d[4]; bf16x8 v; } ahu, alu;
            ahu.d[0] = __builtin_amdgcn_perm(A.y, A.x, 0x05040100u);
            alu.d[0] = __builtin_amdgcn_perm(A.y, A.x, 0x07060302u);
            ahu.d[1] = __builtin_amdgcn_perm(A.w, A.z, 0x05040100u);
            alu.d[1] = __builtin_amdgcn_perm(A.w, A.z, 0x07060302u);
            ahu.d[2] = __builtin_amdgcn_perm(B.y, B.x, 0x05040100u);
            alu.d[2] = __builtin_amdgcn_perm(B.y, B.x, 0x07060302u);
            ahu.d[3] = __builtin_amdgcn_perm(B.w, B.z, 0x05040100u);
            alu.d[3] = __builtin_amdgcn_perm(B.w, B.z, 0x07060302u);
            bf16x8 ah = ahu.v, al = alu.v;
            #pragma unroll
            for (int nb = 0; nb < 2; ++nb) {
                acc[mb][nb] = __builtin_amdgcn_mfma_f32_16x16x32_bf16(ah, bh[nb][ks], acc[mb][nb], 0, 0, 0);
                acc[mb][nb] = __builtin_amdgcn_mfma_f32_16x16x32_bf16(ah, bl[nb][ks], acc[mb][nb], 0, 0, 0);
                acc[mb][nb] = __builtin_amdgcn_mfma_f32_16x16x32_bf16(al, bh[nb][ks], acc[mb][nb], 0, 0, 0);
            }
        }
    }

    // (4) red: aliases first 8KB of this wave's quarter (all reads done)
    {
        float* red_w = (float*)&hs[w][0];   // [64][32]
        #pragma unroll
        for (int mb = 0; mb < 4; ++mb)
            #pragma unroll
            for (int nb = 0; nb < 2; ++nb)
                #pragma unroll
                for (int r = 0; r < 4; ++r)
                    red_w[(mb * 16 + lc * 4 + r) * 32 + nb * 16 + lr] = acc[mb][nb][r];
    }
    __syncthreads();

    // (5) cell phase: 2 cells per thread (red via quarter aliases)
    const float* red0 = (const float*)&hs[0][0];
    const float* red1 = (const float*)&hs[1][0];
    const float* red2 = (const float*)&hs[2][0];
    const float* red3 = (const float*)&hs[3][0];
    #pragma unroll
    for (int e = 0; e < 2; ++e) {
        int b  = e ? b1_ : b0_;
        int jl = e ? jl1 : jl0;
        int jg = e ? jg1 : jg0;
        int nb4 = b * 32 + jl * 4;
        float gi = red0[nb4 + 0] + red1[nb4 + 0] + red2[nb4 + 0] + red3[nb4 + 0];
        float gf = red0[nb4 + 1] + red1[nb4 + 1] + red2[nb4 + 1] + red3[nb4 + 1];
        float gg = red0[nb4 + 2] + red1[nb4 + 2] + red2[nb4 + 2] + red3[nb4 + 2];
        float go = red0[nb4 + 3] + red1[nb4 + 3] + red2[nb4 + 3] + red3[nb4 + 3];
        const float4 xgv = e ? xgv1 : xgv0;
        gi += xgv.x; gf += xgv.y; gg += xgv.z; go += xgv.w;
        size_t sidx = (size_t)b * HDIM + jg;
        float c_reg = e ? cr1 : cr0;
        float i_s = sigm_fast(gi);
        float f_s = sigm_fast(gf);
        float o_s = sigm_fast(go);
        float c_new = f_s * c_reg + i_s * tanh_fast(gg);
        float h_new = o_s * tanh_fast(c_new);
        h_new *= (e ? mh1 : mh0);
        c_new *= (e ? mc1 : mc0);
        c_state[sidx] = c_new;
        h_sum[sidx] += h_new;
        unsigned short hh = f2bf(h_new);
        unsigned short hl2 = f2bf(h_new - bf2f(hh));
        h_pk[nxt + sidx] = (unsigned)hh | ((unsigned)hl2 << 16);
    }
}

// ---------------------------------------------------------------------------
// Projection: WG g handles batch b = g -> out[g*11 + cl]
// ---------------------------------------------------------------------------
__global__ __launch_bounds__(256) void proj_kernel(
        const float* __restrict__ h_sum,
        const float* __restrict__ W_out, const float* __restrict__ b_out,
        float* __restrict__ out) {
    __shared__ float rbuf[NCLS * 256];
    int g = blockIdx.x, tid = threadIdx.x;
    float part[NCLS];
    #pragma unroll
    for (int cl = 0; cl < NCLS; ++cl) part[cl] = 0.f;
    for (int j = tid; j < HDIM; j += 256) {
        float hv = h_sum[g * HDIM + j] * (1.f / T_STEPS);
        #pragma unroll
        for (int cl = 0; cl < NCLS; ++cl)
            part[cl] += hv * W_out[cl * HDIM + j];
    }
    #pragma unroll
    for (int cl = 0; cl < NCLS; ++cl) rbuf[cl * 256 + tid] = part[cl];
    __syncthreads();
    if (tid < NCLS) {
        float s = b_out[tid];
        for (int i = 0; i < 256; ++i) s += rbuf[tid * 256 + i];
        out[g * NCLS + tid] = s;
    }
}

// ---------------------------------------------------------------------------
extern "C" void kernel_launch(void* const* d_in, const int* in_sizes, int n_in,
                              void* d_out, int out_size, void* d_ws, size_t ws_size,
                              hipStream_t stream) {
    const float* x      = (const float*)d_in[0];
    const float* h0     = (const float*)d_in[1];
    const float* c0     = (const float*)d_in[2];
    const float* W_ih   = (const float*)d_in[3];
    const float* W_hh   = (const float*)d_in[4];
    const float* b_ih   = (const float*)d_in[5];
    const float* b_hh   = (const float*)d_in[6];
    const float* W_out  = (const float*)d_in[7];
    const float* b_out  = (const float*)d_in[8];
    const float* mask_h = (const float*)d_in[9];
    const float* mask_c = (const float*)d_in[10];
    float* out = (float*)d_out;

    char* ws = (char*)d_ws;
    float*          xg      = (float*)(ws + 0);                  // 67,108,864 B
    unsigned short* wih_hi  = (unsigned short*)(ws + 67108864);  // 8,388,608
    unsigned short* wih_lo  = (unsigned short*)(ws + 75497472);  // 8,388,608
    unsigned short* whh_hi  = (unsigned short*)(ws + 83886080);  // 2,097,152
    unsigned short* whh_lo  = (unsigned short*)(ws + 85983232);  // 2,097,152
    float*          bc      = (float*)(ws + 88080384);           // 8,192
    unsigned int*   h_pk    = (unsigned int*)(ws + 88088576);    // 262,144 (2 bufs)
    float*          c_state = (float*)(ws + 88350720);           // 131,072
    float*          h_sum   = (float*)(ws + 88481792);           // 131,072
    unsigned short* xs_hi   = (unsigned short*)(ws + 88612864);  // 33,554,432
    unsigned short* xs_lo   = (unsigned short*)(ws + 122167296); // 33,554,432
    const size_t NEED_V2 = 155721728;

    prep_kernel<<<8192, 256, 0, stream>>>(W_ih, W_hh, b_ih, b_hh, h0, c0,
                                          wih_hi, wih_lo, whh_hi, whh_lo, bc,
                                          h_pk, c_state, h_sum);
    if (ws_size >= NEED_V2) {
        prep_xsplit<<<4096, 256, 0, stream>>>(x, xs_hi, xs_lo);
        gemm_xg_v2<<<1024, 256, 0, stream>>>(xs_hi, xs_lo, wih_hi, wih_lo, bc, xg);
    } else {
        gemm_xg<<<1024, 256, 0, stream>>>(x, wih_hi, wih_lo, bc, xg);
    }

    for (int t = 0; t < T_STEPS; ++t)
        lstm_step<<<64, 256, 0, stream>>>(whh_hi, whh_lo, xg, mask_h, mask_c,
                                          h_pk, c_state, h_sum, t);

    proj_kernel<<<64, 256, 0, stream>>>(h_sum, W_out, b_out, out);
}